// Round 4
// baseline (476.737 us; speedup 1.0000x reference)
//
#include <hip/hip_runtime.h>
#include <math.h>
#include <stdint.h>

// N=65536 pos (16x64x64), K=512 slots, D=64.
// out: z_q [16,64,64,64] | idx [16,64,64] | KL | commit   (floats)
#define IDX_OFF 4194304
#define KL_OFF  4259840
#define CM_OFF  4259841
#define LOG_K   6.238324625039508f
#define THR     2.0f

typedef _Float16 half8 __attribute__((ext_vector_type(8)));
typedef _Float16 half4 __attribute__((ext_vector_type(4)));
typedef float    f32x4 __attribute__((ext_vector_type(4)));

// ws layout (element = _Float16 unless noted):
//   LAh [32 g][2 kc][64 lane][8 j]   logits A-frag h-plane   @ half 0
//   LAl [same]                        logits A-frag l-plane   @ half 32768
//   QAh [32 g][64 lane][4 cg][4 j]   z_q A-frag h-plane       @ half 65536
//   CC  [512] float                   codebook norms          @ half 98304
// Logits A-frag: A[row=slot&15][k=c] with k = kc*32 + quad*8 + j, lane = quad*16 + (slot&15)
// z_q   A-frag: A[row=c&15][k=slot&15] with k = quad2*4 + j2,     lane = quad2*16 + (c&15)
__global__ __launch_bounds__(64) void vq_pack(const float* __restrict__ cbk, void* __restrict__ ws){
  _Float16* LAh = (_Float16*)ws;
  _Float16* LAl = LAh + 32768;
  _Float16* QAh = LAl + 32768;
  float*    CCw = (float*)(QAh + 32768);
  const int slot = blockIdx.x, c = threadIdx.x;
  const float x = cbk[(slot << 6) + c];
  const _Float16 h = (_Float16)x;
  const _Float16 l = (_Float16)(x - (float)h);
  const int g = slot >> 4;
  { // logits fragment
    const int kc = c >> 5, quad = (c >> 3) & 3, j = c & 7;
    const int lane = (quad << 4) | (slot & 15);
    const int idx = ((((g << 1) | kc) << 6) | lane) * 8 + j;
    LAh[idx] = h; LAl[idx] = l;
  }
  { // z_q fragment
    const int quad2 = (slot >> 2) & 3, j2 = slot & 3;
    const int cg = c >> 4;
    const int lane = (quad2 << 4) | (c & 15);
    QAh[(((g << 6) | lane) << 4) | (cg << 2) | j2] = h;
  }
  float s = x * x;
#pragma unroll
  for (int m = 1; m < 64; m <<= 1) s += __shfl_xor(s, m, 64);
  if (c == 0) CCw[slot] = s;
}

// 8 waves/block: 4 pos-groups x 2 slot-halves (256 slots each). 8192 waves total
// = 32 waves/CU (full occupancy). Halves merge once at the end via LDS.
// Swapped-operand logits MFMA: D[row=slot(quad*4+r)][col=pos(l15)] -> e is directly
// the B-fragment of the 16x16x16 z_q MFMA (k=quad*4+r, col=pos).
__global__ __launch_bounds__(512, 8) void vq_main(
    const float* __restrict__ ze, const float* __restrict__ uin,
    const void* __restrict__ ws, float* __restrict__ out)
{
  __shared__ float LX[4*22*64];   // [pair pg][word][lane] cross-half exchange
  __shared__ float RED[8];
  const _Float16* wsp = (const _Float16*)ws;
  const half8* LAh = (const half8*)wsp;              // [ (g*2+kc)*64 + lane ]
  const half8* LAl = (const half8*)(wsp + 32768);
  const half8* QA8 = (const half8*)(wsp + 65536);    // [ ((g*64+lane)*2 + b ]
  const float* CCw = (const float*)(wsp + 98304);

  const int tid  = threadIdx.x;
  const int lane = tid & 63, l15 = lane & 15, quad = lane >> 4;
  const int wv   = tid >> 6, pg = wv & 3, half = wv >> 2;
  const int n    = (blockIdx.x << 6) | (pg << 4) | l15;   // this lane's position
  const int bb   = n >> 12, hh = (n >> 6) & 63, w = n & 63;

  // ---- z B-fragments (col=pos=l15, k = kc*32 + quad*8 + j), 2-plane f16 split
  const float* zp = ze + ((size_t)bb << 18) + (hh << 6) + w;
  half8 zh[2], zl[2];
  float zz = 0.f;
#pragma unroll
  for (int kc = 0; kc < 2; ++kc)
#pragma unroll
    for (int j = 0; j < 8; ++j){
      const float x = zp[(size_t)((kc << 5) + (quad << 3) + j) << 12];
      zz = fmaf(x, x, zz);
      const _Float16 h = (_Float16)x;
      zh[kc][j] = h;
      zl[kc][j] = (_Float16)(x - (float)h);
    }
  zz += __shfl_xor(zz, 16, 64);
  zz += __shfl_xor(zz, 32, 64);   // ||z||^2 for this lane's pos

  // per-lane online-softmax state over this half's 256 slots
  float m1 = -3.0e38f, s1 = 0.f, s2s = 0.f, t1s = 0.f, am = -3.0e38f;
  int   ki = 0;
  f32x4 zq0 = {0.f,0.f,0.f,0.f}, zq1 = {0.f,0.f,0.f,0.f};
  f32x4 zq2 = {0.f,0.f,0.f,0.f}, zq3 = {0.f,0.f,0.f,0.f};

  const float* uB = uin + ((size_t)n << 9) + (half << 8) + (quad << 2);
  const int gbase = half << 4;

#pragma unroll 2
  for (int g = 0; g < 16; ++g){
    const int gl = gbase + g;
    // ---- all loads up front (u: HBM/L3 stream; frags+CC: L2-hot table)
    const float4 uf = *(const float4*)(uB + (g << 4));
    const float4 c4 = *(const float4*)(CCw + (gl << 4) + (quad << 2));
    const half8 ch0 = LAh[((gl << 1) | 0) * 64 + lane];
    const half8 ch1 = LAh[((gl << 1) | 1) * 64 + lane];
    const half8 cl0 = LAl[((gl << 1) | 0) * 64 + lane];
    const half8 cl1 = LAl[((gl << 1) | 1) * 64 + lane];
    const half8 qa01 = QA8[((gl << 6) | lane) * 2 + 0];
    const half8 qa23 = QA8[((gl << 6) | lane) * 2 + 1];

    // ---- logits: D[slot=quad*4+r][pos=l15], 3-term f16 split (hh + lh + hl)
    f32x4 acc = {0.f,0.f,0.f,0.f};
    acc = __builtin_amdgcn_mfma_f32_16x16x32_f16(ch0, zh[0], acc, 0,0,0);
    acc = __builtin_amdgcn_mfma_f32_16x16x32_f16(cl0, zh[0], acc, 0,0,0);
    acc = __builtin_amdgcn_mfma_f32_16x16x32_f16(ch0, zl[0], acc, 0,0,0);
    acc = __builtin_amdgcn_mfma_f32_16x16x32_f16(ch1, zh[1], acc, 0,0,0);
    acc = __builtin_amdgcn_mfma_f32_16x16x32_f16(cl1, zh[1], acc, 0,0,0);
    acc = __builtin_amdgcn_mfma_f32_16x16x32_f16(ch1, zl[1], acc, 0,0,0);

    const float ua[4] = {uf.x, uf.y, uf.z, uf.w};
    const float ca[4] = {c4.x, c4.y, c4.z, c4.w};
    float lg[4], lu[4], av[4];
#pragma unroll
    for (int r = 0; r < 4; ++r){
      lg[r] = fmaf(2.f, acc[r], -ca[r] - zz);          // logit = -dist
      lu[r] = 1e-10f - __logf(ua[r] + 1e-10f);         // -log(u+eps)+eps
      av[r] = lg[r] - __logf(lu[r]);                   // a = logit + gumbel
    }
    // per-pos max across this g's 16 slots: in-lane 4 + cross-quad (pos=l15 shared)
    float pm = fmaxf(fmaxf(av[0], av[1]), fmaxf(av[2], av[3]));
    pm = fmaxf(pm, __shfl_xor(pm, 16, 64));
    pm = fmaxf(pm, __shfl_xor(pm, 32, 64));
    if (pm > m1 + THR){                                // defer-max (e <= e^4, f16-safe)
      const float sc = __expf(m1 - pm), sc2 = sc * sc; // e-scale = sc^2 (T=0.5)
      s1 *= sc2; s2s *= sc; t1s *= sc;
      zq0 *= sc2; zq1 *= sc2; zq2 *= sc2; zq3 *= sc2;
      m1 = pm;
    }
    half4 ef;
    const int sb = (gl << 4) | (quad << 2);
#pragma unroll
    for (int r = 0; r < 4; ++r){
      const float t = __expf(av[r] - m1);              // exp(a - M)
      const float e = t * t;                           // exp(2(a-M)) : gumbel weight
      s1 += e;
      ef[r] = (_Float16)e;
      const float p = t * lu[r];                       // = exp(l - M), exact
      s2s += p;
      t1s = fmaf(p, lg[r], t1s);
      if (av[r] > am){ am = av[r]; ki = sb + r; }      // strict: earliest k wins ties
    }
    // ---- z_q: D[c=cg*16+quad*4+r][pos=l15]; ef is already the B-fragment
    const half4 qa0 = __builtin_shufflevector(qa01, qa01, 0,1,2,3);
    const half4 qa1 = __builtin_shufflevector(qa01, qa01, 4,5,6,7);
    const half4 qa2 = __builtin_shufflevector(qa23, qa23, 0,1,2,3);
    const half4 qa3 = __builtin_shufflevector(qa23, qa23, 4,5,6,7);
    zq0 = __builtin_amdgcn_mfma_f32_16x16x16f16(qa0, ef, zq0, 0,0,0);
    zq1 = __builtin_amdgcn_mfma_f32_16x16x16f16(qa1, ef, zq1, 0,0,0);
    zq2 = __builtin_amdgcn_mfma_f32_16x16x16f16(qa2, ef, zq2, 0,0,0);
    zq3 = __builtin_amdgcn_mfma_f32_16x16x16f16(qa3, ef, zq3, 0,0,0);
  }

  // ---- cross-quad combine (same pos lives in lanes l15, l15+16, +32, +48)
#pragma unroll
  for (int m = 16; m < 64; m <<= 1){
    s1  += __shfl_xor(s1,  m, 64);
    s2s += __shfl_xor(s2s, m, 64);
    t1s += __shfl_xor(t1s, m, 64);
    const float vo = __shfl_xor(am, m, 64);
    const int   io = __shfl_xor(ki, m, 64);
    if (vo > am || (vo == am && io < ki)){ am = vo; ki = io; }
  }

  // ---- cross-half merge via LDS (exact online-softmax merge)
  float* X = &LX[(pg * 22) * 64 + lane];
  if (half == 1){
#pragma unroll
    for (int r = 0; r < 4; ++r){
      X[(r     ) << 6] = zq0[r];
      X[(r +  4) << 6] = zq1[r];
      X[(r +  8) << 6] = zq2[r];
      X[(r + 12) << 6] = zq3[r];
    }
    X[16 << 6] = s1;  X[17 << 6] = s2s; X[18 << 6] = t1s;
    X[19 << 6] = m1;  X[20 << 6] = am;  X[21 << 6] = __int_as_float(ki);
  }
  __syncthreads();
  if (half == 0){
    const float m1B = X[19 << 6];
    const float M   = fmaxf(m1, m1B);
    const float sA  = __expf(m1 - M),  sB  = __expf(m1B - M);
    const float sA2 = sA * sA,         sB2 = sB * sB;
    s1  = s1  * sA2 + X[16 << 6] * sB2;
    s2s = s2s * sA  + X[17 << 6] * sB;
    t1s = t1s * sA  + X[18 << 6] * sB;
    const float amB = X[20 << 6];
    const int   kiB = __float_as_int(X[21 << 6]);
    if (amB > am || (amB == am && kiB < ki)){ am = amB; ki = kiB; }
    m1 = M;
#pragma unroll
    for (int r = 0; r < 4; ++r){
      zq0[r] = zq0[r] * sA2 + X[(r     ) << 6] * sB2;
      zq1[r] = zq1[r] * sA2 + X[(r +  4) << 6] * sB2;
      zq2[r] = zq2[r] * sA2 + X[(r +  8) << 6] * sB2;
      zq3[r] = zq3[r] * sA2 + X[(r + 12) << 6] * sB2;
    }

    const float inv = 1.0f / s1;
    const float pl  = t1s / s2s;                        // sum p*logit (normalized)
    float kl = pl + LOG_K - m1 - __logf(s2s);           // sum p*(log p + logK)
    float cm = -pl;                                     // sum p*dist
    if (quad == 0) out[IDX_OFF + n] = (float)ki;

    // ---- z_q store: lane holds 16 channels of its pos
    float* ob = out + ((size_t)bb << 18) + (hh << 6) + w;
#pragma unroll
    for (int r = 0; r < 4; ++r){
      const int cb = (quad << 2) + r;
      ob[(size_t)(cb     ) << 12] = zq0[r] * inv;
      ob[(size_t)(cb + 16) << 12] = zq1[r] * inv;
      ob[(size_t)(cb + 32) << 12] = zq2[r] * inv;
      ob[(size_t)(cb + 48) << 12] = zq3[r] * inv;
    }

    // ---- KL/commit wave reduction (quads hold duplicates -> keep quad0 only)
    if (quad != 0){ kl = 0.f; cm = 0.f; }
#pragma unroll
    for (int m = 1; m < 64; m <<= 1){ kl += __shfl_xor(kl, m, 64); cm += __shfl_xor(cm, m, 64); }
    if (lane == 0){ RED[pg] = kl; RED[pg + 4] = cm; }
  }
  __syncthreads();
  if (tid == 0){
    atomicAdd(out + KL_OFF, (RED[0]+RED[1]+RED[2]+RED[3]) * 0.0625f);
    atomicAdd(out + CM_OFF, (RED[4]+RED[5]+RED[6]+RED[7]) * 0.0625f);
  }
}

extern "C" void kernel_launch(void* const* d_in, const int* in_sizes, int n_in,
                              void* d_out, int out_size, void* d_ws, size_t ws_size,
                              hipStream_t stream){
  const float* ze  = (const float*)d_in[0];
  const float* cbk = (const float*)d_in[1];
  const float* uin = (const float*)d_in[2];
  float* out = (float*)d_out;
  hipMemsetAsync(out + KL_OFF, 0, 2 * sizeof(float), stream);
  vq_pack<<<dim3(512), dim3(64), 0, stream>>>(cbk, d_ws);
  vq_main<<<dim3(1024), dim3(512), 0, stream>>>(ze, uin, d_ws, out);
}

// Round 5
// 440.535 us; speedup vs baseline: 1.0822x; 1.0822x over previous
//
#include <hip/hip_runtime.h>
#include <math.h>
#include <stdint.h>

// N=65536 pos (16x64x64), K=512 slots, D=64.
// out: z_q [16,64,64,64] | idx [16,64,64] | KL | commit   (floats)
#define IDX_OFF 4194304
#define KL_OFF  4259840
#define CM_OFF  4259841
#define LOG_K   6.238324625039508f
#define THR     2.0f

typedef _Float16 half8 __attribute__((ext_vector_type(8)));
typedef _Float16 half4 __attribute__((ext_vector_type(4)));
typedef float    f32x4 __attribute__((ext_vector_type(4)));

// ws layout (element = _Float16 unless noted):
//   LAh [32 g][2 kc][64 lane][8 j]   logits A-frag h-plane   @ half 0
//   LAl [same]                        logits A-frag l-plane   @ half 32768
//   QAh [32 g][64 lane][4 cg][4 j]   z_q A-frag h-plane       @ half 65536
//   CC  [512] float                   codebook norms          @ half 98304
// Logits A-frag: A[row=slot&15][k=c] with k = kc*32 + quad*8 + j, lane = quad*16 + (slot&15)
// z_q   A-frag: A[row=c&15][k=slot&15] with k = quad2*4 + j2,     lane = quad2*16 + (c&15)
__global__ __launch_bounds__(64) void vq_pack(const float* __restrict__ cbk, void* __restrict__ ws){
  _Float16* LAh = (_Float16*)ws;
  _Float16* LAl = LAh + 32768;
  _Float16* QAh = LAl + 32768;
  float*    CCw = (float*)(QAh + 32768);
  const int slot = blockIdx.x, c = threadIdx.x;
  const float x = cbk[(slot << 6) + c];
  const _Float16 h = (_Float16)x;
  const _Float16 l = (_Float16)(x - (float)h);
  const int g = slot >> 4;
  { // logits fragment
    const int kc = c >> 5, quad = (c >> 3) & 3, j = c & 7;
    const int lane = (quad << 4) | (slot & 15);
    const int idx = ((((g << 1) | kc) << 6) | lane) * 8 + j;
    LAh[idx] = h; LAl[idx] = l;
  }
  { // z_q fragment
    const int quad2 = (slot >> 2) & 3, j2 = slot & 3;
    const int cg = c >> 4;
    const int lane = (quad2 << 4) | (c & 15);
    QAh[(((g << 6) | lane) << 4) | (cg << 2) | j2] = h;
  }
  float s = x * x;
#pragma unroll
  for (int m = 1; m < 64; m <<= 1) s += __shfl_xor(s, m, 64);
  if (c == 0) CCw[slot] = s;
}

// 8 waves/block: 4 pos-groups x 2 slot-halves (256 slots each). 8192 waves total.
// launch_bounds min-waves=6 (VGPR cap ~84): body needs ~60-70 VGPRs; the hard
// 8-wave pin (cap 64) caused catastrophic scratch spill (474MB writes, round 4).
// Swapped-operand logits MFMA: D[row=slot(quad*4+r)][col=pos(l15)] -> e is directly
// the B-fragment of the 16x16x16 z_q MFMA (k=quad*4+r, col=pos).
__global__ __launch_bounds__(512, 6) void vq_main(
    const float* __restrict__ ze, const float* __restrict__ uin,
    const void* __restrict__ ws, float* __restrict__ out)
{
  __shared__ float LX[4*22*64];   // [pair pg][word][lane] cross-half exchange
  __shared__ float RED[8];
  const _Float16* wsp = (const _Float16*)ws;
  const half8* LAh = (const half8*)wsp;              // [ (g*2+kc)*64 + lane ]
  const half8* LAl = (const half8*)(wsp + 32768);
  const half8* QA8 = (const half8*)(wsp + 65536);    // [ (g*64+lane)*2 + b ]
  const float* CCw = (const float*)(wsp + 98304);

  const int tid  = threadIdx.x;
  const int lane = tid & 63, l15 = lane & 15, quad = lane >> 4;
  const int wv   = tid >> 6, pg = wv & 3, half = wv >> 2;
  const int n    = (blockIdx.x << 6) | (pg << 4) | l15;   // this lane's position
  const int bb   = n >> 12, hh = (n >> 6) & 63, w = n & 63;

  // ---- z B-fragments (col=pos=l15, k = kc*32 + quad*8 + j), 2-plane f16 split
  const float* zp = ze + ((size_t)bb << 18) + (hh << 6) + w;
  half8 zh[2], zl[2];
  float zz = 0.f;
#pragma unroll
  for (int kc = 0; kc < 2; ++kc)
#pragma unroll
    for (int j = 0; j < 8; ++j){
      const float x = zp[(size_t)((kc << 5) + (quad << 3) + j) << 12];
      zz = fmaf(x, x, zz);
      const _Float16 h = (_Float16)x;
      zh[kc][j] = h;
      zl[kc][j] = (_Float16)(x - (float)h);
    }
  zz += __shfl_xor(zz, 16, 64);
  zz += __shfl_xor(zz, 32, 64);   // ||z||^2 for this lane's pos

  // per-lane online-softmax state over this half's 256 slots
  float m1 = -3.0e38f, s1 = 0.f, s2s = 0.f, t1s = 0.f, am = -3.0e38f;
  int   ki = 0;
  f32x4 zq0 = {0.f,0.f,0.f,0.f}, zq1 = {0.f,0.f,0.f,0.f};
  f32x4 zq2 = {0.f,0.f,0.f,0.f}, zq3 = {0.f,0.f,0.f,0.f};

  const float* uB = uin + ((size_t)n << 9) + (half << 8) + (quad << 2);
  const int gbase = half << 4;

#pragma unroll 2
  for (int g = 0; g < 16; ++g){
    const int gl = gbase + g;
    // ---- all loads up front (u: HBM/L3 stream; frags+CC: L2-hot table)
    const float4 uf = *(const float4*)(uB + (g << 4));
    const float4 c4 = *(const float4*)(CCw + (gl << 4) + (quad << 2));
    const half8 ch0 = LAh[((gl << 1) | 0) * 64 + lane];
    const half8 ch1 = LAh[((gl << 1) | 1) * 64 + lane];
    const half8 cl0 = LAl[((gl << 1) | 0) * 64 + lane];
    const half8 cl1 = LAl[((gl << 1) | 1) * 64 + lane];
    const half8 qa01 = QA8[((gl << 6) | lane) * 2 + 0];
    const half8 qa23 = QA8[((gl << 6) | lane) * 2 + 1];

    // ---- logits: D[slot=quad*4+r][pos=l15], 3-term f16 split (hh + lh + hl)
    f32x4 acc = {0.f,0.f,0.f,0.f};
    acc = __builtin_amdgcn_mfma_f32_16x16x32_f16(ch0, zh[0], acc, 0,0,0);
    acc = __builtin_amdgcn_mfma_f32_16x16x32_f16(cl0, zh[0], acc, 0,0,0);
    acc = __builtin_amdgcn_mfma_f32_16x16x32_f16(ch0, zl[0], acc, 0,0,0);
    acc = __builtin_amdgcn_mfma_f32_16x16x32_f16(ch1, zh[1], acc, 0,0,0);
    acc = __builtin_amdgcn_mfma_f32_16x16x32_f16(cl1, zh[1], acc, 0,0,0);
    acc = __builtin_amdgcn_mfma_f32_16x16x32_f16(ch1, zl[1], acc, 0,0,0);

    const float ua[4] = {uf.x, uf.y, uf.z, uf.w};
    const float ca[4] = {c4.x, c4.y, c4.z, c4.w};
    float lg[4], lu[4], av[4];
#pragma unroll
    for (int r = 0; r < 4; ++r){
      lg[r] = fmaf(2.f, acc[r], -ca[r] - zz);          // logit = -dist
      lu[r] = 1e-10f - __logf(ua[r] + 1e-10f);         // -log(u+eps)+eps
      av[r] = lg[r] - __logf(lu[r]);                   // a = logit + gumbel
    }
    // per-pos max across this g's 16 slots: in-lane 4 + cross-quad (pos=l15 shared)
    float pm = fmaxf(fmaxf(av[0], av[1]), fmaxf(av[2], av[3]));
    pm = fmaxf(pm, __shfl_xor(pm, 16, 64));
    pm = fmaxf(pm, __shfl_xor(pm, 32, 64));
    if (pm > m1 + THR){                                // defer-max (e <= e^4, f16-safe)
      const float sc = __expf(m1 - pm), sc2 = sc * sc; // e-scale = sc^2 (T=0.5)
      s1 *= sc2; s2s *= sc; t1s *= sc;
      zq0 *= sc2; zq1 *= sc2; zq2 *= sc2; zq3 *= sc2;
      m1 = pm;
    }
    half4 ef;
    const int sb = (gl << 4) | (quad << 2);
#pragma unroll
    for (int r = 0; r < 4; ++r){
      const float t = __expf(av[r] - m1);              // exp(a - M)
      const float e = t * t;                           // exp(2(a-M)) : gumbel weight
      s1 += e;
      ef[r] = (_Float16)e;
      const float p = t * lu[r];                       // = exp(l - M), exact
      s2s += p;
      t1s = fmaf(p, lg[r], t1s);
      if (av[r] > am){ am = av[r]; ki = sb + r; }      // strict: earliest k wins ties
    }
    // ---- z_q: D[c=cg*16+quad*4+r][pos=l15]; ef is already the B-fragment
    const half4 qa0 = __builtin_shufflevector(qa01, qa01, 0,1,2,3);
    const half4 qa1 = __builtin_shufflevector(qa01, qa01, 4,5,6,7);
    const half4 qa2 = __builtin_shufflevector(qa23, qa23, 0,1,2,3);
    const half4 qa3 = __builtin_shufflevector(qa23, qa23, 4,5,6,7);
    zq0 = __builtin_amdgcn_mfma_f32_16x16x16f16(qa0, ef, zq0, 0,0,0);
    zq1 = __builtin_amdgcn_mfma_f32_16x16x16f16(qa1, ef, zq1, 0,0,0);
    zq2 = __builtin_amdgcn_mfma_f32_16x16x16f16(qa2, ef, zq2, 0,0,0);
    zq3 = __builtin_amdgcn_mfma_f32_16x16x16f16(qa3, ef, zq3, 0,0,0);
  }

  // ---- cross-quad combine (same pos lives in lanes l15, l15+16, +32, +48)
#pragma unroll
  for (int m = 16; m < 64; m <<= 1){
    s1  += __shfl_xor(s1,  m, 64);
    s2s += __shfl_xor(s2s, m, 64);
    t1s += __shfl_xor(t1s, m, 64);
    const float vo = __shfl_xor(am, m, 64);
    const int   io = __shfl_xor(ki, m, 64);
    if (vo > am || (vo == am && io < ki)){ am = vo; ki = io; }
  }

  // ---- cross-half merge via LDS (exact online-softmax merge)
  float* X = &LX[(pg * 22) * 64 + lane];
  if (half == 1){
#pragma unroll
    for (int r = 0; r < 4; ++r){
      X[(r     ) << 6] = zq0[r];
      X[(r +  4) << 6] = zq1[r];
      X[(r +  8) << 6] = zq2[r];
      X[(r + 12) << 6] = zq3[r];
    }
    X[16 << 6] = s1;  X[17 << 6] = s2s; X[18 << 6] = t1s;
    X[19 << 6] = m1;  X[20 << 6] = am;  X[21 << 6] = __int_as_float(ki);
  }
  __syncthreads();
  if (half == 0){
    const float m1B = X[19 << 6];
    const float M   = fmaxf(m1, m1B);
    const float sA  = __expf(m1 - M),  sB  = __expf(m1B - M);
    const float sA2 = sA * sA,         sB2 = sB * sB;
    s1  = s1  * sA2 + X[16 << 6] * sB2;
    s2s = s2s * sA  + X[17 << 6] * sB;
    t1s = t1s * sA  + X[18 << 6] * sB;
    const float amB = X[20 << 6];
    const int   kiB = __float_as_int(X[21 << 6]);
    if (amB > am || (amB == am && kiB < ki)){ am = amB; ki = kiB; }
    m1 = M;
#pragma unroll
    for (int r = 0; r < 4; ++r){
      zq0[r] = zq0[r] * sA2 + X[(r     ) << 6] * sB2;
      zq1[r] = zq1[r] * sA2 + X[(r +  4) << 6] * sB2;
      zq2[r] = zq2[r] * sA2 + X[(r +  8) << 6] * sB2;
      zq3[r] = zq3[r] * sA2 + X[(r + 12) << 6] * sB2;
    }

    const float inv = 1.0f / s1;
    const float pl  = t1s / s2s;                        // sum p*logit (normalized)
    float kl = pl + LOG_K - m1 - __logf(s2s);           // sum p*(log p + logK)
    float cm = -pl;                                     // sum p*dist
    if (quad == 0) out[IDX_OFF + n] = (float)ki;

    // ---- z_q store: lane holds 16 channels of its pos
    float* ob = out + ((size_t)bb << 18) + (hh << 6) + w;
#pragma unroll
    for (int r = 0; r < 4; ++r){
      const int cb = (quad << 2) + r;
      ob[(size_t)(cb     ) << 12] = zq0[r] * inv;
      ob[(size_t)(cb + 16) << 12] = zq1[r] * inv;
      ob[(size_t)(cb + 32) << 12] = zq2[r] * inv;
      ob[(size_t)(cb + 48) << 12] = zq3[r] * inv;
    }

    // ---- KL/commit wave reduction (quads hold duplicates -> keep quad0 only)
    if (quad != 0){ kl = 0.f; cm = 0.f; }
#pragma unroll
    for (int m = 1; m < 64; m <<= 1){ kl += __shfl_xor(kl, m, 64); cm += __shfl_xor(cm, m, 64); }
    if (lane == 0){ RED[pg] = kl; RED[pg + 4] = cm; }
  }
  __syncthreads();
  if (tid == 0){
    atomicAdd(out + KL_OFF, (RED[0]+RED[1]+RED[2]+RED[3]) * 0.0625f);
    atomicAdd(out + CM_OFF, (RED[4]+RED[5]+RED[6]+RED[7]) * 0.0625f);
  }
}

extern "C" void kernel_launch(void* const* d_in, const int* in_sizes, int n_in,
                              void* d_out, int out_size, void* d_ws, size_t ws_size,
                              hipStream_t stream){
  const float* ze  = (const float*)d_in[0];
  const float* cbk = (const float*)d_in[1];
  const float* uin = (const float*)d_in[2];
  float* out = (float*)d_out;
  hipMemsetAsync(out + KL_OFF, 0, 2 * sizeof(float), stream);
  vq_pack<<<dim3(512), dim3(64), 0, stream>>>(cbk, d_ws);
  vq_main<<<dim3(1024), dim3(512), 0, stream>>>(ze, uin, d_ws, out);
}

// Round 6
// 249.000 us; speedup vs baseline: 1.9146x; 1.7692x over previous
//
#include <hip/hip_runtime.h>
#include <math.h>
#include <stdint.h>

// N=65536 pos (16x64x64), K=512 slots, D=64.
// out: z_q [16,64,64,64] | idx [16,64,64] | KL | commit   (floats)
#define IDX_OFF 4194304
#define KL_OFF  4259840
#define CM_OFF  4259841
#define LOG_K   6.238324625039508f
#define THR     2.0f

typedef _Float16 half8 __attribute__((ext_vector_type(8)));
typedef _Float16 half4 __attribute__((ext_vector_type(4)));
typedef float    f32x4 __attribute__((ext_vector_type(4)));

// ws layout (element = _Float16 unless noted):
//   LAh [32 g][2 kc][64 lane][8 j]   logits A-frag h-plane   @ half 0
//   LAl [same]                        logits A-frag l-plane   @ half 32768
//   QAh [32 g][64 lane][4 cg][4 j]   z_q A-frag h-plane       @ half 65536
//   CC  [512] float                   codebook norms          @ half 98304
// Logits A-frag: A[row=slot&15][k=c] with k = kc*32 + quad*8 + j, lane = quad*16 + (slot&15)
// z_q   A-frag: A[row=c&15][k=slot&15] with k = quad2*4 + j2,     lane = quad2*16 + (c&15)
__global__ __launch_bounds__(64) void vq_pack(const float* __restrict__ cbk, void* __restrict__ ws){
  _Float16* LAh = (_Float16*)ws;
  _Float16* LAl = LAh + 32768;
  _Float16* QAh = LAl + 32768;
  float*    CCw = (float*)(QAh + 32768);
  const int slot = blockIdx.x, c = threadIdx.x;
  const float x = cbk[(slot << 6) + c];
  const _Float16 h = (_Float16)x;
  const _Float16 l = (_Float16)(x - (float)h);
  const int g = slot >> 4;
  { // logits fragment
    const int kc = c >> 5, quad = (c >> 3) & 3, j = c & 7;
    const int lane = (quad << 4) | (slot & 15);
    const int idx = ((((g << 1) | kc) << 6) | lane) * 8 + j;
    LAh[idx] = h; LAl[idx] = l;
  }
  { // z_q fragment
    const int quad2 = (slot >> 2) & 3, j2 = slot & 3;
    const int cg = c >> 4;
    const int lane = (quad2 << 4) | (c & 15);
    QAh[(((g << 6) | lane) << 4) | (cg << 2) | j2] = h;
  }
  float s = x * x;
#pragma unroll
  for (int m = 1; m < 64; m <<= 1) s += __shfl_xor(s, m, 64);
  if (c == 0) CCw[slot] = s;
}

// 8 waves/block: 4 pos-groups x 2 slot-halves (256 slots each). 8192 waves total.
// __launch_bounds__ 2nd arg is MIN-BLOCKS-PER-CU on this compiler (measured:
// (512,8)->32 VGPR cap, (512,6)->40 — fits blocks/CU, not waves/EU). 3 blocks
// x 8 waves = 24 waves/CU = 6/SIMD -> VGPR cap ~84; body needs ~60-70 -> no spill.
// Swapped-operand logits MFMA: D[row=slot(quad*4+r)][col=pos(l15)] -> e is directly
// the B-fragment of the 16x16x16 z_q MFMA (k=quad*4+r, col=pos).
__global__ __launch_bounds__(512, 3) void vq_main(
    const float* __restrict__ ze, const float* __restrict__ uin,
    const void* __restrict__ ws, float* __restrict__ out)
{
  __shared__ float LX[4*22*64];   // [pair pg][word][lane] cross-half exchange
  __shared__ float RED[8];
  const _Float16* wsp = (const _Float16*)ws;
  const half8* LAh = (const half8*)wsp;              // [ (g*2+kc)*64 + lane ]
  const half8* LAl = (const half8*)(wsp + 32768);
  const half8* QA8 = (const half8*)(wsp + 65536);    // [ (g*64+lane)*2 + b ]
  const float* CCw = (const float*)(wsp + 98304);

  const int tid  = threadIdx.x;
  const int lane = tid & 63, l15 = lane & 15, quad = lane >> 4;
  const int wv   = tid >> 6, pg = wv & 3, half = wv >> 2;
  const int n    = (blockIdx.x << 6) | (pg << 4) | l15;   // this lane's position
  const int bb   = n >> 12, hh = (n >> 6) & 63, w = n & 63;

  // ---- z B-fragments (col=pos=l15, k = kc*32 + quad*8 + j), 2-plane f16 split
  const float* zp = ze + ((size_t)bb << 18) + (hh << 6) + w;
  half8 zh[2], zl[2];
  float zz = 0.f;
#pragma unroll
  for (int kc = 0; kc < 2; ++kc)
#pragma unroll
    for (int j = 0; j < 8; ++j){
      const float x = zp[(size_t)((kc << 5) + (quad << 3) + j) << 12];
      zz = fmaf(x, x, zz);
      const _Float16 h = (_Float16)x;
      zh[kc][j] = h;
      zl[kc][j] = (_Float16)(x - (float)h);
    }
  zz += __shfl_xor(zz, 16, 64);
  zz += __shfl_xor(zz, 32, 64);   // ||z||^2 for this lane's pos

  // per-lane online-softmax state over this half's 256 slots
  float m1 = -3.0e38f, s1 = 0.f, s2s = 0.f, t1s = 0.f, am = -3.0e38f;
  int   ki = 0;
  f32x4 zq0 = {0.f,0.f,0.f,0.f}, zq1 = {0.f,0.f,0.f,0.f};
  f32x4 zq2 = {0.f,0.f,0.f,0.f}, zq3 = {0.f,0.f,0.f,0.f};

  const float* uB = uin + ((size_t)n << 9) + (half << 8) + (quad << 2);
  const int gbase = half << 4;

#pragma unroll 2
  for (int g = 0; g < 16; ++g){
    const int gl = gbase + g;
    // ---- all loads up front (u: HBM/L3 stream; frags+CC: L2-hot table)
    const float4 uf = *(const float4*)(uB + (g << 4));
    const float4 c4 = *(const float4*)(CCw + (gl << 4) + (quad << 2));
    const half8 ch0 = LAh[((gl << 1) | 0) * 64 + lane];
    const half8 ch1 = LAh[((gl << 1) | 1) * 64 + lane];
    const half8 cl0 = LAl[((gl << 1) | 0) * 64 + lane];
    const half8 cl1 = LAl[((gl << 1) | 1) * 64 + lane];
    const half8 qa01 = QA8[((gl << 6) | lane) * 2 + 0];
    const half8 qa23 = QA8[((gl << 6) | lane) * 2 + 1];

    // ---- logits: D[slot=quad*4+r][pos=l15], 3-term f16 split (hh + lh + hl)
    f32x4 acc = {0.f,0.f,0.f,0.f};
    acc = __builtin_amdgcn_mfma_f32_16x16x32_f16(ch0, zh[0], acc, 0,0,0);
    acc = __builtin_amdgcn_mfma_f32_16x16x32_f16(cl0, zh[0], acc, 0,0,0);
    acc = __builtin_amdgcn_mfma_f32_16x16x32_f16(ch0, zl[0], acc, 0,0,0);
    acc = __builtin_amdgcn_mfma_f32_16x16x32_f16(ch1, zh[1], acc, 0,0,0);
    acc = __builtin_amdgcn_mfma_f32_16x16x32_f16(cl1, zh[1], acc, 0,0,0);
    acc = __builtin_amdgcn_mfma_f32_16x16x32_f16(ch1, zl[1], acc, 0,0,0);

    const float ua[4] = {uf.x, uf.y, uf.z, uf.w};
    const float ca[4] = {c4.x, c4.y, c4.z, c4.w};
    float lg[4], lu[4], av[4];
#pragma unroll
    for (int r = 0; r < 4; ++r){
      lg[r] = fmaf(2.f, acc[r], -ca[r] - zz);          // logit = -dist
      lu[r] = 1e-10f - __logf(ua[r] + 1e-10f);         // -log(u+eps)+eps
      av[r] = lg[r] - __logf(lu[r]);                   // a = logit + gumbel
    }
    // per-pos max across this g's 16 slots: in-lane 4 + cross-quad (pos=l15 shared)
    float pm = fmaxf(fmaxf(av[0], av[1]), fmaxf(av[2], av[3]));
    pm = fmaxf(pm, __shfl_xor(pm, 16, 64));
    pm = fmaxf(pm, __shfl_xor(pm, 32, 64));
    if (pm > m1 + THR){                                // defer-max (e <= e^4, f16-safe)
      const float sc = __expf(m1 - pm), sc2 = sc * sc; // e-scale = sc^2 (T=0.5)
      s1 *= sc2; s2s *= sc; t1s *= sc;
      zq0 *= sc2; zq1 *= sc2; zq2 *= sc2; zq3 *= sc2;
      m1 = pm;
    }
    half4 ef;
    const int sb = (gl << 4) | (quad << 2);
#pragma unroll
    for (int r = 0; r < 4; ++r){
      const float t = __expf(av[r] - m1);              // exp(a - M)
      const float e = t * t;                           // exp(2(a-M)) : gumbel weight
      s1 += e;
      ef[r] = (_Float16)e;
      const float p = t * lu[r];                       // = exp(l - M), exact
      s2s += p;
      t1s = fmaf(p, lg[r], t1s);
      if (av[r] > am){ am = av[r]; ki = sb + r; }      // strict: earliest k wins ties
    }
    // ---- z_q: D[c=cg*16+quad*4+r][pos=l15]; ef is already the B-fragment
    const half4 qa0 = __builtin_shufflevector(qa01, qa01, 0,1,2,3);
    const half4 qa1 = __builtin_shufflevector(qa01, qa01, 4,5,6,7);
    const half4 qa2 = __builtin_shufflevector(qa23, qa23, 0,1,2,3);
    const half4 qa3 = __builtin_shufflevector(qa23, qa23, 4,5,6,7);
    zq0 = __builtin_amdgcn_mfma_f32_16x16x16f16(qa0, ef, zq0, 0,0,0);
    zq1 = __builtin_amdgcn_mfma_f32_16x16x16f16(qa1, ef, zq1, 0,0,0);
    zq2 = __builtin_amdgcn_mfma_f32_16x16x16f16(qa2, ef, zq2, 0,0,0);
    zq3 = __builtin_amdgcn_mfma_f32_16x16x16f16(qa3, ef, zq3, 0,0,0);
  }

  // ---- cross-quad combine (same pos lives in lanes l15, l15+16, +32, +48)
#pragma unroll
  for (int m = 16; m < 64; m <<= 1){
    s1  += __shfl_xor(s1,  m, 64);
    s2s += __shfl_xor(s2s, m, 64);
    t1s += __shfl_xor(t1s, m, 64);
    const float vo = __shfl_xor(am, m, 64);
    const int   io = __shfl_xor(ki, m, 64);
    if (vo > am || (vo == am && io < ki)){ am = vo; ki = io; }
  }

  // ---- cross-half merge via LDS (exact online-softmax merge)
  float* X = &LX[(pg * 22) * 64 + lane];
  if (half == 1){
#pragma unroll
    for (int r = 0; r < 4; ++r){
      X[(r     ) << 6] = zq0[r];
      X[(r +  4) << 6] = zq1[r];
      X[(r +  8) << 6] = zq2[r];
      X[(r + 12) << 6] = zq3[r];
    }
    X[16 << 6] = s1;  X[17 << 6] = s2s; X[18 << 6] = t1s;
    X[19 << 6] = m1;  X[20 << 6] = am;  X[21 << 6] = __int_as_float(ki);
  }
  __syncthreads();
  if (half == 0){
    const float m1B = X[19 << 6];
    const float M   = fmaxf(m1, m1B);
    const float sA  = __expf(m1 - M),  sB  = __expf(m1B - M);
    const float sA2 = sA * sA,         sB2 = sB * sB;
    s1  = s1  * sA2 + X[16 << 6] * sB2;
    s2s = s2s * sA  + X[17 << 6] * sB;
    t1s = t1s * sA  + X[18 << 6] * sB;
    const float amB = X[20 << 6];
    const int   kiB = __float_as_int(X[21 << 6]);
    if (amB > am || (amB == am && kiB < ki)){ am = amB; ki = kiB; }
    m1 = M;
#pragma unroll
    for (int r = 0; r < 4; ++r){
      zq0[r] = zq0[r] * sA2 + X[(r     ) << 6] * sB2;
      zq1[r] = zq1[r] * sA2 + X[(r +  4) << 6] * sB2;
      zq2[r] = zq2[r] * sA2 + X[(r +  8) << 6] * sB2;
      zq3[r] = zq3[r] * sA2 + X[(r + 12) << 6] * sB2;
    }

    const float inv = 1.0f / s1;
    const float pl  = t1s / s2s;                        // sum p*logit (normalized)
    float kl = pl + LOG_K - m1 - __logf(s2s);           // sum p*(log p + logK)
    float cm = -pl;                                     // sum p*dist
    if (quad == 0) out[IDX_OFF + n] = (float)ki;

    // ---- z_q store: lane holds 16 channels of its pos
    float* ob = out + ((size_t)bb << 18) + (hh << 6) + w;
#pragma unroll
    for (int r = 0; r < 4; ++r){
      const int cb = (quad << 2) + r;
      ob[(size_t)(cb     ) << 12] = zq0[r] * inv;
      ob[(size_t)(cb + 16) << 12] = zq1[r] * inv;
      ob[(size_t)(cb + 32) << 12] = zq2[r] * inv;
      ob[(size_t)(cb + 48) << 12] = zq3[r] * inv;
    }

    // ---- KL/commit wave reduction (quads hold duplicates -> keep quad0 only)
    if (quad != 0){ kl = 0.f; cm = 0.f; }
#pragma unroll
    for (int m = 1; m < 64; m <<= 1){ kl += __shfl_xor(kl, m, 64); cm += __shfl_xor(cm, m, 64); }
    if (lane == 0){ RED[pg] = kl; RED[pg + 4] = cm; }
  }
  __syncthreads();
  if (tid == 0){
    atomicAdd(out + KL_OFF, (RED[0]+RED[1]+RED[2]+RED[3]) * 0.0625f);
    atomicAdd(out + CM_OFF, (RED[4]+RED[5]+RED[6]+RED[7]) * 0.0625f);
  }
}

extern "C" void kernel_launch(void* const* d_in, const int* in_sizes, int n_in,
                              void* d_out, int out_size, void* d_ws, size_t ws_size,
                              hipStream_t stream){
  const float* ze  = (const float*)d_in[0];
  const float* cbk = (const float*)d_in[1];
  const float* uin = (const float*)d_in[2];
  float* out = (float*)d_out;
  hipMemsetAsync(out + KL_OFF, 0, 2 * sizeof(float), stream);
  vq_pack<<<dim3(512), dim3(64), 0, stream>>>(cbk, d_ws);
  vq_main<<<dim3(1024), dim3(512), 0, stream>>>(ze, uin, d_ws, out);
}